// Round 5
// baseline (8425.973 us; speedup 1.0000x reference)
//
#include <hip/hip_runtime.h>
#include <hip/hip_bf16.h>
#include <stdint.h>

#define T_LEN 4096
#define D_DIM 256
#define HDIM 256
#define G4 1024          // 4*HD gate rows per direction
#define NTAGS 32
#define START_TAG 30
#define STOP_TAG 31

typedef unsigned long long u64;
typedef unsigned int u32;

__device__ __forceinline__ float sigf(float x){ return 1.0f/(1.0f+expf(-x)); }

// ---------------------------------------------------------------------------
// K1: embedding gather + input projections xg = E[seq] @ Wih^T + (bih+bhh)
// ---------------------------------------------------------------------------
__global__ __launch_bounds__(256) void k_xg(const int* __restrict__ seq,
    const float* __restrict__ E,
    const float* __restrict__ Wf, const float* __restrict__ bihf, const float* __restrict__ bhhf,
    const float* __restrict__ Wb, const float* __restrict__ bihb, const float* __restrict__ bhhb,
    float* __restrict__ xg_f, float* __restrict__ xg_b)
{
    __shared__ __align__(16) float xsh[8][D_DIM];
    __shared__ int sq[8];
    const int b = blockIdx.x, tb = b >> 3, cb = b & 7, j = threadIdx.x;
    if (j < 8) sq[j] = seq[tb*8 + j];
    __syncthreads();
    #pragma unroll
    for (int r = 0; r < 8; ++r) xsh[r][j] = E[(size_t)sq[r]*D_DIM + j];
    __syncthreads();
    const int col = cb*256 + j;      // 0..2047
    const int d   = col >> 10;       // 0 fwd, 1 bwd
    const int row = col & 1023;
    const float* W = d ? Wb : Wf;
    const float bias = d ? (bihb[row] + bhhb[row]) : (bihf[row] + bhhf[row]);
    const float4* wr = reinterpret_cast<const float4*>(W + (size_t)row*D_DIM);
    float acc[8];
    #pragma unroll
    for (int r=0;r<8;++r) acc[r] = 0.f;
    for (int kk = 0; kk < D_DIM/4; ++kk){
        float4 wv = wr[kk];
        #pragma unroll
        for (int r=0;r<8;++r){
            float4 xv = reinterpret_cast<const float4*>(xsh[r])[kk];
            acc[r] = fmaf(wv.x, xv.x, fmaf(wv.y, xv.y, fmaf(wv.z, xv.z, fmaf(wv.w, xv.w, acc[r]))));
        }
    }
    #pragma unroll
    for (int r=0;r<8;++r){
        const int t = tb*8 + r;
        const float v = acc[r] + bias;
        if (d == 0) xg_f[(size_t)t*G4 + row] = v;
        else        xg_b[(size_t)(T_LEN-1-t)*G4 + row] = v;
    }
}

// ---------------------------------------------------------------------------
// K2: bidirectional LSTM recurrence. 32 persistent blocks (2 dir x 16).
// Each block owns 16 units = 64 gate rows. r5 structural change: weights are
// LDS-RESIDENT, stored TRANSPOSED [k][row_local] so the per-k ds_read_b32
// across 64 consecutive rows is conflict-free (2 lanes/bank = free, m136).
// r1-r4 proved the register allocator will not keep a >=128-VGPR weight
// array resident (VGPR_Count 88-184; remat re-streamed 131-256KB/step
// through L1 = ~2000-4100 cy/step). LDS residency is deterministic.
// K is split 4-ways across the 4 waves (q = j>>6); per-row partials are
// combined through a small LDS buffer; xg is folded into the q==0 partial.
// Cross-block h exchange: r1-proven packed (tag<<32|h) relaxed agent-scope
// atomics, parity double-buffered, tight poll.
// ---------------------------------------------------------------------------
__global__ __launch_bounds__(256,1) void k_lstm(
    const float* __restrict__ Whh_f, const float* __restrict__ Whh_b,
    const float* __restrict__ xgf, const float* __restrict__ xgb,
    const float* __restrict__ h0, const float* __restrict__ c0,
    float* __restrict__ hs_f, float* __restrict__ hs_b,
    u64* __restrict__ hbuf_all)
{
    const int blk = blockIdx.x;       // 0..31
    const int d   = blk >> 4;         // direction
    const int sb  = blk & 15;         // sub-block within direction
    const int ulo = sb * 16;          // first owned unit
    const int j = threadIdx.x;        // 0..255
    const int r = j & 63;             // row_local in [0,64)
    const int q = j >> 6;             // k-quarter (== wave id)
    const int g_r = r >> 4;           // gate of this row (0:i 1:f 2:g 3:o)
    const int u_r = r & 15;           // unit offset of this row
    const int row_global = g_r*256 + ulo + u_r;   // in [0,1024)

    const float* __restrict__ Whh = d ? Whh_b : Whh_f;
    const float* __restrict__ xg  = d ? xgb : xgf;
    float* __restrict__ hs = d ? hs_b : hs_f;
    u64* __restrict__ hb = hbuf_all + (size_t)d*2*HDIM;   // [parity][unit]

    __shared__ float w_lds[256*64];   // [k][row_local], 64 KB
    __shared__ float partial[4*64];   // [q][row_local]
    __shared__ float h_sh[HDIM];

    // ---- stage weights into LDS, transposed ----
    {
        const float* wsrc = Whh + (size_t)row_global*HDIM + q*64;
        #pragma unroll
        for (int kk = 0; kk < 64; kk += 4){
            float4 wv = *reinterpret_cast<const float4*>(wsrc + kk);
            w_lds[(q*64+kk+0)*64 + r] = wv.x;   // lanes = 64 consecutive rows: conflict-free
            w_lds[(q*64+kk+1)*64 + r] = wv.y;
            w_lds[(q*64+kk+2)*64 + r] = wv.z;
            w_lds[(q*64+kk+3)*64 + r] = wv.w;
        }
    }
    h_sh[j] = h0[d*HDIM + j];
    float c = (j < 16) ? c0[d*HDIM + ulo + j] : 0.0f;
    float xgc = (q == 0) ? xg[row_global] : 0.0f;   // xg[0][row], only q==0 uses it
    __syncthreads();

    for (int t = 0; t < T_LEN; ++t){
        // ---- matvec: partial[q][r] = (q==0 ? xg : 0) + sum_{k in quarter} W[r][k]*h[k]
        float acc = (q == 0) ? xgc : 0.0f;
        {
            const float* hp = h_sh + q*64;
            const float* wp = w_lds + (q*64)*64 + r;
            #pragma unroll
            for (int kk = 0; kk < 64; ++kk)
                acc = fmaf(wp[kk*64], hp[kk], acc);   // w: conflict-free; h: broadcast
        }
        partial[q*64 + r] = acc;
        if (q == 0 && t+1 < T_LEN) xgc = xg[(size_t)(t+1)*G4 + row_global];
        __syncthreads();              // A: partials ready, h_sh reads done
        const int par = (t+1) & 1;
        if (j < 16){                  // gate threads: unit ulo+j
            float s[4];
            #pragma unroll
            for (int g = 0; g < 4; ++g){
                const int rr = g*16 + j;
                s[g] = (partial[rr] + partial[64+rr]) + (partial[128+rr] + partial[192+rr]);
            }
            const float ig = sigf(s[0]);
            const float fg = sigf(s[1]);
            const float gg = tanhf(s[2]);
            const float og = sigf(s[3]);
            c = fg*c + ig*gg;
            const float h = og*tanhf(c);
            const int ug = ulo + j;
            const u64 pk = ((u64)(u32)(t+1) << 32) | (u64)__float_as_uint(h);
            __hip_atomic_store(&hb[par*HDIM + ug], pk, __ATOMIC_RELAXED, __HIP_MEMORY_SCOPE_AGENT);
            h_sh[ug] = h;
            hs[(size_t)(d==0 ? t : (T_LEN-1-t))*HDIM + ug] = h;
        }
        if (t+1 < T_LEN){
            const int u = j;          // unit this thread waits for (incl. j<16 if foreign)
            if (u < ulo || u >= ulo+16){
                const u32 want = (u32)(t+1);
                u64* p = &hb[par*HDIM + u];
                u64 pk = __hip_atomic_load(p, __ATOMIC_RELAXED, __HIP_MEMORY_SCOPE_AGENT);
                while ((u32)(pk >> 32) != want){
                    pk = __hip_atomic_load(p, __ATOMIC_RELAXED, __HIP_MEMORY_SCOPE_AGENT);
                }
                h_sh[u] = __uint_as_float((u32)pk);
            }
        }
        __syncthreads();              // B: h_sh = h_t complete
    }
}

// ---------------------------------------------------------------------------
// K3: feats[t][tag] = [hf[t]; hb[t]] . W_out[tag] + b_out[tag]  (f32)
// ---------------------------------------------------------------------------
__global__ __launch_bounds__(256) void k_feats(
    const float* __restrict__ hs_f, const float* __restrict__ hs_b,
    const float* __restrict__ W_out, const float* __restrict__ b_out,
    float* __restrict__ feats)
{
    __shared__ __align__(16) float fsh[8][512];
    const int tb = blockIdx.x, j = threadIdx.x;
    #pragma unroll
    for (int r=0;r<8;++r){
        const int t = tb*8 + r;
        fsh[r][j]       = hs_f[(size_t)t*HDIM + j];
        fsh[r][256 + j] = hs_b[(size_t)t*HDIM + j];
    }
    __syncthreads();
    const int tsub = j >> 5, tag = j & 31;
    const float4* wr = reinterpret_cast<const float4*>(W_out + (size_t)tag*512);
    float acc = b_out[tag];
    for (int kk=0; kk<128; ++kk){
        float4 wvv = wr[kk];
        float4 hv = reinterpret_cast<const float4*>(fsh[tsub])[kk];
        acc = fmaf(wvv.x, hv.x, fmaf(wvv.y, hv.y, fmaf(wvv.z, hv.z, fmaf(wvv.w, hv.w, acc))));
    }
    feats[(size_t)(tb*8+tsub)*NTAGS + tag] = acc;
}

// ---------------------------------------------------------------------------
// K4: Viterbi in f32 (threshold analysis: path flips cost <=31 << 183, score
// tolerance 183). Wave 0 scans; waves 1-3 double-buffer feat chunks. Then
// LDS-chunked serial backtrace.
// ---------------------------------------------------------------------------
__global__ __launch_bounds__(256,1) void k_viterbi(
    const float* __restrict__ feats, const float* __restrict__ trans,
    unsigned char* __restrict__ bp_g, float* __restrict__ out)
{
    __shared__ __align__(16) float fbuf[2][256*NTAGS];   // 2 x 32KB
    __shared__ float fv_sh[NTAGS];
    __shared__ float term_sh[NTAGS];
    __shared__ int best_sh;
    const int j = threadIdx.x;
    const int n = j & 31, ph = (j >> 5) & 1;
    const bool scanlane = (j < 64);
    float tr[16];
    if (scanlane){
        #pragma unroll
        for (int i=0;i<16;++i) tr[i] = trans[n*NTAGS + ph*16 + i];
    }
    float fv = (n == START_TAG) ? 0.0f : -10000.0f;

    const int CH = 256, NCH = T_LEN / CH;  // 16 chunks
    for (int idx = j; idx < CH*NTAGS; idx += 256) fbuf[0][idx] = feats[idx];
    __syncthreads();
    for (int cc = 0; cc < NCH; ++cc){
        const int buf = cc & 1;
        if (scanlane){
            for (int s = 0; s < CH; ++s){
                const int t = cc*CH + s;
                const float f = fbuf[buf][s*NTAGS + n];
                if (ph == 0) fv_sh[n] = fv;      // same-wave lockstep publish
                float bestv = -1e30f; int bestp = 0;
                #pragma unroll
                for (int i=0;i<16;++i){
                    const int p = ph*16 + i;
                    const float v = fv_sh[p] + tr[i];
                    if (v > bestv){ bestv = v; bestp = p; }   // strict > = first index
                }
                const float ov = __shfl_xor(bestv, 32, 64);
                const int   op = __shfl_xor(bestp, 32, 64);
                const float lowv  = ph ? ov    : bestv;
                const int   lowp  = ph ? op    : bestp;
                const float highv = ph ? bestv : ov;
                const int   highp = ph ? bestp : op;
                float wvv = lowv; int wp = lowp;
                if (highv > lowv){ wvv = highv; wp = highp; } // low half wins ties
                if (ph == 0) bp_g[(size_t)t*NTAGS + n] = (unsigned char)wp;
                fv = wvv + f;
            }
        } else if (cc + 1 < NCH){
            const int nb = (cc+1) & 1;
            const float* src = feats + (size_t)(cc+1)*CH*NTAGS;
            for (int idx = j - 64; idx < CH*NTAGS; idx += 192) fbuf[nb][idx] = src[idx];
        }
        __syncthreads();
    }

    if (scanlane && ph == 0) term_sh[n] = fv + trans[STOP_TAG*NTAGS + n];
    __syncthreads();
    if (j == 0){
        float bv = term_sh[0]; int bi = 0;
        for (int p = 1; p < NTAGS; ++p){
            if (term_sh[p] > bv){ bv = term_sh[p]; bi = p; }
        }
        out[0] = bv;
        out[1 + (T_LEN-1)] = (float)bi;
        best_sh = bi;
    }
    __syncthreads();
    // backtrace, 1024-step LDS chunks
    unsigned char* bp_sh = reinterpret_cast<unsigned char*>(fbuf);
    int b = best_sh;
    for (int cc2 = 3; cc2 >= 0; --cc2){
        const u32* src = reinterpret_cast<const u32*>(bp_g + (size_t)cc2*1024*NTAGS);
        u32* dst = reinterpret_cast<u32*>(bp_sh);
        for (int idx = j; idx < 8192; idx += 256) dst[idx] = src[idx];
        __syncthreads();
        if (j == 0){
            for (int tt = 1023; tt >= 0; --tt){
                const int t = cc2*1024 + tt;
                if (t == 0) break;                 // step into <START> dropped
                const int nb2 = bp_sh[tt*NTAGS + b];
                out[1 + (t-1)] = (float)nb2;
                b = nb2;
            }
        }
        __syncthreads();
    }
}

// ---------------------------------------------------------------------------
extern "C" void kernel_launch(void* const* d_in, const int* in_sizes, int n_in,
                              void* d_out, int out_size, void* d_ws, size_t ws_size,
                              hipStream_t stream)
{
    const int*   seq   = (const int*)  d_in[0];
    const float* E     = (const float*)d_in[1];
    const float* Wih_f = (const float*)d_in[2];
    const float* Whh_f = (const float*)d_in[3];
    const float* bih_f = (const float*)d_in[4];
    const float* bhh_f = (const float*)d_in[5];
    const float* Wih_b = (const float*)d_in[6];
    const float* Whh_b = (const float*)d_in[7];
    const float* bih_b = (const float*)d_in[8];
    const float* bhh_b = (const float*)d_in[9];
    const float* h0    = (const float*)d_in[10];
    const float* c0    = (const float*)d_in[11];
    const float* W_out = (const float*)d_in[12];
    const float* b_out = (const float*)d_in[13];
    const float* trans = (const float*)d_in[14];

    char* ws = (char*)d_ws;
    float* xg_f  = (float*)(ws);                                 // 16 MB
    float* xg_b  = (float*)(ws + (size_t)(16u<<20));             // 16 MB
    float* hs_f  = (float*)(ws + (size_t)(32u<<20));             // 4 MB
    float* hs_b  = (float*)(ws + (size_t)(36u<<20));             // 4 MB
    float* feats = (float*)(ws + (size_t)(40u<<20));             // 512 KB
    unsigned char* bp = (unsigned char*)(ws + (size_t)(40u<<20) + (512u<<10)); // 128 KB
    u64* hbuf    = (u64*)(ws + (size_t)(40u<<20) + (640u<<10));  // 8 KB

    k_xg<<<dim3(4096), dim3(256), 0, stream>>>(seq, E, Wih_f, bih_f, bhh_f,
                                               Wih_b, bih_b, bhh_b, xg_f, xg_b);
    k_lstm<<<dim3(32), dim3(256), 0, stream>>>(Whh_f, Whh_b, xg_f, xg_b, h0, c0, hs_f, hs_b, hbuf);
    k_feats<<<dim3(512), dim3(256), 0, stream>>>(hs_f, hs_b, W_out, b_out, feats);
    k_viterbi<<<dim3(1), dim3(256), 0, stream>>>(feats, trans, bp, (float*)d_out);
}

// Round 6
// 6950.009 us; speedup vs baseline: 1.2124x; 1.2124x over previous
//
#include <hip/hip_runtime.h>
#include <hip/hip_bf16.h>
#include <stdint.h>

#define T_LEN 4096
#define D_DIM 256
#define HDIM 256
#define G4 1024          // 4*HD gate rows per direction
#define NTAGS 32
#define START_TAG 30
#define STOP_TAG 31

typedef unsigned long long u64;
typedef unsigned int u32;

__device__ __forceinline__ float sigf(float x){ return 1.0f/(1.0f+expf(-x)); }

// ---------------------------------------------------------------------------
// K1: embedding gather + input projections xg = E[seq] @ Wih^T + (bih+bhh)
// ---------------------------------------------------------------------------
__global__ __launch_bounds__(256) void k_xg(const int* __restrict__ seq,
    const float* __restrict__ E,
    const float* __restrict__ Wf, const float* __restrict__ bihf, const float* __restrict__ bhhf,
    const float* __restrict__ Wb, const float* __restrict__ bihb, const float* __restrict__ bhhb,
    float* __restrict__ xg_f, float* __restrict__ xg_b)
{
    __shared__ __align__(16) float xsh[8][D_DIM];
    __shared__ int sq[8];
    const int b = blockIdx.x, tb = b >> 3, cb = b & 7, j = threadIdx.x;
    if (j < 8) sq[j] = seq[tb*8 + j];
    __syncthreads();
    #pragma unroll
    for (int r = 0; r < 8; ++r) xsh[r][j] = E[(size_t)sq[r]*D_DIM + j];
    __syncthreads();
    const int col = cb*256 + j;      // 0..2047
    const int d   = col >> 10;       // 0 fwd, 1 bwd
    const int row = col & 1023;
    const float* W = d ? Wb : Wf;
    const float bias = d ? (bihb[row] + bhhb[row]) : (bihf[row] + bhhf[row]);
    const float4* wr = reinterpret_cast<const float4*>(W + (size_t)row*D_DIM);
    float acc[8];
    #pragma unroll
    for (int r=0;r<8;++r) acc[r] = 0.f;
    for (int kk = 0; kk < D_DIM/4; ++kk){
        float4 wv = wr[kk];
        #pragma unroll
        for (int r=0;r<8;++r){
            float4 xv = reinterpret_cast<const float4*>(xsh[r])[kk];
            acc[r] = fmaf(wv.x, xv.x, fmaf(wv.y, xv.y, fmaf(wv.z, xv.z, fmaf(wv.w, xv.w, acc[r]))));
        }
    }
    #pragma unroll
    for (int r=0;r<8;++r){
        const int t = tb*8 + r;
        const float v = acc[r] + bias;
        if (d == 0) xg_f[(size_t)t*G4 + row] = v;
        else        xg_b[(size_t)(T_LEN-1-t)*G4 + row] = v;
    }
}

// ---------------------------------------------------------------------------
// K2: bidirectional LSTM recurrence. 64 persistent blocks (2 dir x 32).
// Each block owns 8 units = 32 gate rows. r6 structural redesign:
//  * ONE barrier/step. Thread j polls exactly unit j; wave w thus fills the
//    wave-PRIVATE h slice [w*64,(w+1)*64) that its own dot products consume
//    -> ds_write + s_waitcnt lgkmcnt(0), no block barrier for h.
//  * Weights LDS-resident, row-major [32][256] f32, XOR-swizzled
//    (byte ^= (r&7)<<4) so ds_read_b128 across 32 rows is conflict-free
//    (unswizzled = all lanes same bank, 32-way). 32KB/step at the BW floor.
//  * Wave-parallel gates: lanes 0..31 of wave 0 do one nonlinearity each,
//    3 shfls combine, lanes 0..7 update c,h, publish, write hs.
//  * partial[] parity double-buffered -> no write-after-read race across the
//    single barrier. Skew safety: publish of tag t+3 transitively requires
//    all blocks consumed tag t+1 (poll success chain), so slot reuse is safe.
// Exchange: r1-proven packed (tag<<32|h_bits) relaxed agent-scope atomics,
// parity double-buffered, tight poll. Replay-safe: stale tags are either
// never-matching or carry bit-identical values (deterministic kernel).
// ---------------------------------------------------------------------------
__global__ __launch_bounds__(256,1) void k_lstm(
    const float* __restrict__ Whh_f, const float* __restrict__ Whh_b,
    const float* __restrict__ xgf, const float* __restrict__ xgb,
    const float* __restrict__ h0, const float* __restrict__ c0,
    float* __restrict__ hs_f, float* __restrict__ hs_b,
    u64* __restrict__ hbuf_all)
{
    const int blk = blockIdx.x;       // 0..63
    const int d   = blk >> 5;         // direction
    const int sb  = blk & 31;         // sub-block within direction
    const int ulo = sb * 8;           // first owned unit
    const int j = threadIdx.x;        // 0..255
    const int r = j & 31;             // row_local in [0,32)
    const int o = j >> 5;             // k-slice (32 k each), o in [0,8)
    const int g_r = r >> 3;           // gate of this row
    const int u_r = r & 7;            // unit offset of this row
    const int row_global = g_r*256 + ulo + u_r;   // in [0,1024)

    const float* __restrict__ Whh = d ? Whh_b : Whh_f;
    const float* __restrict__ xg  = d ? xgb : xgf;
    float* __restrict__ hs = d ? hs_b : hs_f;
    u64* __restrict__ hb = hbuf_all + (size_t)d*2*HDIM;   // [parity][unit]

    __shared__ __align__(16) char wbuf[32*1024];  // 32 rows x 256 k f32, swizzled
    __shared__ float h_sh[HDIM];                  // wave w owns [w*64,(w+1)*64)
    __shared__ float partial[2*256];              // [parity][o][r]

    // ---- stage weights (each thread: row r, k-slice o), swizzled ----
    {
        const float4* src = reinterpret_cast<const float4*>(Whh + (size_t)row_global*HDIM + o*32);
        #pragma unroll
        for (int i = 0; i < 8; ++i){
            *reinterpret_cast<float4*>(wbuf + ((r*1024 + (o*8+i)*16) ^ ((r&7)<<4))) = src[i];
        }
    }
    h_sh[j] = h0[d*HDIM + j];
    float c = (j < 8) ? c0[d*HDIM + ulo + j] : 0.0f;
    float xgc = xg[row_global];       // xg[0][row]
    __syncthreads();

    for (int t = 0; t < T_LEN; ++t){
        if (t > 0){
            // poll unit j (tag t), fill wave-private h slice; no barrier needed
            const u32 want = (u32)t;
            u64* p = &hb[(size_t)(t&1)*HDIM + j];
            u64 pk = __hip_atomic_load(p, __ATOMIC_RELAXED, __HIP_MEMORY_SCOPE_AGENT);
            while ((u32)(pk >> 32) != want){
                pk = __hip_atomic_load(p, __ATOMIC_RELAXED, __HIP_MEMORY_SCOPE_AGENT);
            }
            h_sh[j] = __uint_as_float((u32)pk);
            asm volatile("s_waitcnt lgkmcnt(0)" ::: "memory");   // wave-level fence
        }
        // ---- dot: row r, k in [o*32, o*32+32), b128 reads at BW floor ----
        float acc = 0.0f;
        {
            const float4* hvp = reinterpret_cast<const float4*>(h_sh + o*32);
            #pragma unroll
            for (int i = 0; i < 8; ++i){
                float4 wv = *reinterpret_cast<const float4*>(wbuf + ((r*1024 + (o*8+i)*16) ^ ((r&7)<<4)));
                float4 hv = hvp[i];
                acc = fmaf(wv.x, hv.x, fmaf(wv.y, hv.y, fmaf(wv.z, hv.z, fmaf(wv.w, hv.w, acc))));
            }
        }
        partial[(t&1)*256 + o*32 + r] = acc;
        __syncthreads();              // the ONLY barrier per step
        if (j < 32){                  // wave 0: wave-parallel gates
            const int par = t & 1;
            float s = xgc;
            #pragma unroll
            for (int oo = 0; oo < 8; ++oo) s += partial[par*256 + oo*32 + j];
            const float val = (g_r == 2) ? tanhf(s) : sigf(s);
            const float fv_ = __shfl(val,  8 + u_r, 64);
            const float gv_ = __shfl(val, 16 + u_r, 64);
            const float ov_ = __shfl(val, 24 + u_r, 64);
            if (j < 8){
                c = fv_*c + val*gv_;              // val = i-gate for lanes 0..7
                const float h = ov_*tanhf(c);
                const int ug = ulo + j;
                const u64 pk = ((u64)(u32)(t+1) << 32) | (u64)__float_as_uint(h);
                __hip_atomic_store(&hb[(size_t)((t+1)&1)*HDIM + ug], pk,
                                   __ATOMIC_RELAXED, __HIP_MEMORY_SCOPE_AGENT);
                hs[(size_t)(d==0 ? t : (T_LEN-1-t))*HDIM + ug] = h;
            }
            if (t+1 < T_LEN) xgc = xg[(size_t)(t+1)*G4 + row_global];  // prefetch
        }
    }
}

// ---------------------------------------------------------------------------
// K3: feats[t][tag] = [hf[t]; hb[t]] . W_out[tag] + b_out[tag]  (f32)
// ---------------------------------------------------------------------------
__global__ __launch_bounds__(256) void k_feats(
    const float* __restrict__ hs_f, const float* __restrict__ hs_b,
    const float* __restrict__ W_out, const float* __restrict__ b_out,
    float* __restrict__ feats)
{
    __shared__ __align__(16) float fsh[8][512];
    const int tb = blockIdx.x, j = threadIdx.x;
    #pragma unroll
    for (int r=0;r<8;++r){
        const int t = tb*8 + r;
        fsh[r][j]       = hs_f[(size_t)t*HDIM + j];
        fsh[r][256 + j] = hs_b[(size_t)t*HDIM + j];
    }
    __syncthreads();
    const int tsub = j >> 5, tag = j & 31;
    const float4* wr = reinterpret_cast<const float4*>(W_out + (size_t)tag*512);
    float acc = b_out[tag];
    for (int kk=0; kk<128; ++kk){
        float4 wvv = wr[kk];
        float4 hv = reinterpret_cast<const float4*>(fsh[tsub])[kk];
        acc = fmaf(wvv.x, hv.x, fmaf(wvv.y, hv.y, fmaf(wvv.z, hv.z, fmaf(wvv.w, hv.w, acc))));
    }
    feats[(size_t)(tb*8+tsub)*NTAGS + tag] = acc;
}

// ---------------------------------------------------------------------------
// K4: Viterbi in f32 (threshold analysis: path flips cost <=31 << 183, score
// tolerance 183). Wave 0 scans; waves 1-3 double-buffer feat chunks. Then
// LDS-chunked serial backtrace.
// ---------------------------------------------------------------------------
__global__ __launch_bounds__(256,1) void k_viterbi(
    const float* __restrict__ feats, const float* __restrict__ trans,
    unsigned char* __restrict__ bp_g, float* __restrict__ out)
{
    __shared__ __align__(16) float fbuf[2][256*NTAGS];   // 2 x 32KB
    __shared__ float fv_sh[NTAGS];
    __shared__ float term_sh[NTAGS];
    __shared__ int best_sh;
    const int j = threadIdx.x;
    const int n = j & 31, ph = (j >> 5) & 1;
    const bool scanlane = (j < 64);
    float tr[16];
    if (scanlane){
        #pragma unroll
        for (int i=0;i<16;++i) tr[i] = trans[n*NTAGS + ph*16 + i];
    }
    float fv = (n == START_TAG) ? 0.0f : -10000.0f;

    const int CH = 256, NCH = T_LEN / CH;  // 16 chunks
    for (int idx = j; idx < CH*NTAGS; idx += 256) fbuf[0][idx] = feats[idx];
    __syncthreads();
    for (int cc = 0; cc < NCH; ++cc){
        const int buf = cc & 1;
        if (scanlane){
            for (int s = 0; s < CH; ++s){
                const int t = cc*CH + s;
                const float f = fbuf[buf][s*NTAGS + n];
                if (ph == 0) fv_sh[n] = fv;      // same-wave lockstep publish
                float bestv = -1e30f; int bestp = 0;
                #pragma unroll
                for (int i=0;i<16;++i){
                    const int p = ph*16 + i;
                    const float v = fv_sh[p] + tr[i];
                    if (v > bestv){ bestv = v; bestp = p; }   // strict > = first index
                }
                const float ov = __shfl_xor(bestv, 32, 64);
                const int   op = __shfl_xor(bestp, 32, 64);
                const float lowv  = ph ? ov    : bestv;
                const int   lowp  = ph ? op    : bestp;
                const float highv = ph ? bestv : ov;
                const int   highp = ph ? bestp : op;
                float wvv = lowv; int wp = lowp;
                if (highv > lowv){ wvv = highv; wp = highp; } // low half wins ties
                if (ph == 0) bp_g[(size_t)t*NTAGS + n] = (unsigned char)wp;
                fv = wvv + f;
            }
        } else if (cc + 1 < NCH){
            const int nb = (cc+1) & 1;
            const float* src = feats + (size_t)(cc+1)*CH*NTAGS;
            for (int idx = j - 64; idx < CH*NTAGS; idx += 192) fbuf[nb][idx] = src[idx];
        }
        __syncthreads();
    }

    if (scanlane && ph == 0) term_sh[n] = fv + trans[STOP_TAG*NTAGS + n];
    __syncthreads();
    if (j == 0){
        float bv = term_sh[0]; int bi = 0;
        for (int p = 1; p < NTAGS; ++p){
            if (term_sh[p] > bv){ bv = term_sh[p]; bi = p; }
        }
        out[0] = bv;
        out[1 + (T_LEN-1)] = (float)bi;
        best_sh = bi;
    }
    __syncthreads();
    // backtrace, 1024-step LDS chunks
    unsigned char* bp_sh = reinterpret_cast<unsigned char*>(fbuf);
    int b = best_sh;
    for (int cc2 = 3; cc2 >= 0; --cc2){
        const u32* src = reinterpret_cast<const u32*>(bp_g + (size_t)cc2*1024*NTAGS);
        u32* dst = reinterpret_cast<u32*>(bp_sh);
        for (int idx = j; idx < 8192; idx += 256) dst[idx] = src[idx];
        __syncthreads();
        if (j == 0){
            for (int tt = 1023; tt >= 0; --tt){
                const int t = cc2*1024 + tt;
                if (t == 0) break;                 // step into <START> dropped
                const int nb2 = bp_sh[tt*NTAGS + b];
                out[1 + (t-1)] = (float)nb2;
                b = nb2;
            }
        }
        __syncthreads();
    }
}

// ---------------------------------------------------------------------------
extern "C" void kernel_launch(void* const* d_in, const int* in_sizes, int n_in,
                              void* d_out, int out_size, void* d_ws, size_t ws_size,
                              hipStream_t stream)
{
    const int*   seq   = (const int*)  d_in[0];
    const float* E     = (const float*)d_in[1];
    const float* Wih_f = (const float*)d_in[2];
    const float* Whh_f = (const float*)d_in[3];
    const float* bih_f = (const float*)d_in[4];
    const float* bhh_f = (const float*)d_in[5];
    const float* Wih_b = (const float*)d_in[6];
    const float* Whh_b = (const float*)d_in[7];
    const float* bih_b = (const float*)d_in[8];
    const float* bhh_b = (const float*)d_in[9];
    const float* h0    = (const float*)d_in[10];
    const float* c0    = (const float*)d_in[11];
    const float* W_out = (const float*)d_in[12];
    const float* b_out = (const float*)d_in[13];
    const float* trans = (const float*)d_in[14];

    char* ws = (char*)d_ws;
    float* xg_f  = (float*)(ws);                                 // 16 MB
    float* xg_b  = (float*)(ws + (size_t)(16u<<20));             // 16 MB
    float* hs_f  = (float*)(ws + (size_t)(32u<<20));             // 4 MB
    float* hs_b  = (float*)(ws + (size_t)(36u<<20));             // 4 MB
    float* feats = (float*)(ws + (size_t)(40u<<20));             // 512 KB
    unsigned char* bp = (unsigned char*)(ws + (size_t)(40u<<20) + (512u<<10)); // 128 KB
    u64* hbuf    = (u64*)(ws + (size_t)(40u<<20) + (640u<<10));  // 8 KB

    k_xg<<<dim3(4096), dim3(256), 0, stream>>>(seq, E, Wih_f, bih_f, bhh_f,
                                               Wih_b, bih_b, bhh_b, xg_f, xg_b);
    k_lstm<<<dim3(64), dim3(256), 0, stream>>>(Whh_f, Whh_b, xg_f, xg_b, h0, c0, hs_f, hs_b, hbuf);
    k_feats<<<dim3(512), dim3(256), 0, stream>>>(hs_f, hs_b, W_out, b_out, feats);
    k_viterbi<<<dim3(1), dim3(256), 0, stream>>>(feats, trans, bp, (float*)d_out);
}